// Round 9
// baseline (155.804 us; speedup 1.0000x reference)
//
#include <hip/hip_runtime.h>

#define MDIM 2048   // B
#define KD   2560   // HEAD
#define NHID 2048   // N_HID
#define INF  512
#define BK   32
#define NT   80     // K-tiles of 32

typedef __attribute__((ext_vector_type(16))) float f32x16;
typedef __attribute__((ext_vector_type(8))) short short8;
typedef __attribute__((ext_vector_type(8))) unsigned short ushort8v;
typedef __attribute__((ext_vector_type(4))) unsigned short ushort4v;

#define AS1 __attribute__((address_space(1)))
#define AS3 __attribute__((address_space(3)))

__device__ __forceinline__ unsigned short f2bf(float f) {
    unsigned u = __float_as_uint(f);
    u += 0x7fffu + ((u >> 16) & 1u);
    return (unsigned short)(u >> 16);
}

// ---------------- prep: xc = concat(x, hidden) -> bf16 [MDIM][KD] ----------------
__global__ void prep_xc(const float* __restrict__ x, const float* __restrict__ h,
                        unsigned short* __restrict__ xc) {
    int idx = blockIdx.x * 256 + threadIdx.x;
    int e = idx * 8;
    int b = e / KD;
    int c = e - b * KD;
    const float* src = (c < INF) ? (x + (size_t)b * INF + c)
                                 : (h + (size_t)b * NHID + (c - INF));
    float4 v0 = *(const float4*)src;
    float4 v1 = *(const float4*)(src + 4);
    ushort8v o;
    o[0] = f2bf(v0.x); o[1] = f2bf(v0.y); o[2] = f2bf(v0.z); o[3] = f2bf(v0.w);
    o[4] = f2bf(v1.x); o[5] = f2bf(v1.y); o[6] = f2bf(v1.z); o[7] = f2bf(v1.w);
    *(ushort8v*)(xc + e) = o;
}

// ---------------- prep: Wm[k] = W_k * mask -> bf16, 5 planes [5*NHID][KD] ----------------
__global__ void prep_wm(const float* __restrict__ Wg, const float* __restrict__ Wh,
                        const float* __restrict__ Wfg, const float* __restrict__ Wfh,
                        const float* __restrict__ Wp, const float* __restrict__ mask,
                        unsigned short* __restrict__ Wm) {
    int idx = blockIdx.x * 256 + threadIdx.x;
    size_t e = (size_t)idx * 4;
    const size_t PL = (size_t)NHID * KD;
    int col = (int)(e % KD);
    float4 m;
    if (col < INF) m = *(const float4*)(mask + e);
    else           m = make_float4(1.f, 1.f, 1.f, 1.f);
    const float* Ws[5] = {Wg, Wh, Wfg, Wfh, Wp};
    #pragma unroll
    for (int k = 0; k < 5; ++k) {
        float4 w = *(const float4*)(Ws[k] + e);
        ushort4v o;
        o[0] = f2bf(w.x * m.x); o[1] = f2bf(w.y * m.y);
        o[2] = f2bf(w.z * m.z); o[3] = f2bf(w.w * m.w);
        *(ushort4v*)(Wm + k * PL + e) = o;
    }
}

// ---------------- fused GEMM + epilogue, triple-buffered counted-vmcnt pipeline ----
// Round-7 fused structure (256x64x5 tile, 8 waves 4Mx2N, 32x32x16, in-reg
// epilogue) re-plumbed per T4: BK=32, NT=80, THREE LDS buffers (108 KB).
// Tile kt: reads buf kt%3; stages kt+2 -> (kt+2)%3; boundary wait is
// vmcnt(4) (this tile's own 4-5 issues stay in flight; in-order retire
// guarantees everything older - next tile's data - is done). Loads get ~2
// tile-bodies of flight; DMA LDS-writes amortize across tiles; vmcnt(0)
// never in steady state (only at the NT-2 edge).
// Swizzle (BK=32: 4 slots of 16B/row): LDS[r][s] = G[r][s ^ ((r>>1)&3)].
// Write side: slot_src = (lane&3)^((lane>>3)&3) (r0 multiples of 16 fold out).
// Read side: cs = (2s+hi) ^ ((l31>>1)&3) -> 8-lane groups cover all 32 banks,
// 4-way = structural b128 floor.
#define MFMA32(d, va, vb) d = __builtin_amdgcn_mfma_f32_32x32x16_bf16(va, vb, d, 0, 0, 0)

__global__ __launch_bounds__(512, 2) void gemm_fused(
    const unsigned short* __restrict__ A,
    const unsigned short* __restrict__ Bm,
    const float* __restrict__ bg, const float* __restrict__ bh,
    const float* __restrict__ bfg, const float* __restrict__ bfh,
    const float* __restrict__ bp,
    float* __restrict__ out) {
    __shared__ unsigned short lsA[3][256 * BK];   // 48 KB
    __shared__ unsigned short lsB[3][320 * BK];   // 60 KB

    const int tid  = threadIdx.x;
    const int lane = tid & 63;
    const int w    = tid >> 6;       // 0..7
    const int wm   = w >> 1;         // 0..3  (M waves)
    const int wn   = w & 1;          // 0..1  (N col-half)
    const int l31  = lane & 31;
    const int hi   = lane >> 5;      // 0..1
    const int m0   = blockIdx.y * 256;
    const int n0c  = blockIdx.x * 64;

    const unsigned short* gA = A + (size_t)m0 * KD;
    // staging: one instr covers 16 rows x 64B. lane L -> row r0+(L>>2),
    // LDS slot L&3 holds G slot (L&3)^((L>>3)&3) (swizzle key (row>>1)&3).
    const int soff = (lane >> 2) * KD + ((((lane & 3) ^ ((lane >> 3) & 3))) << 3);

#define SA(i, t, b) __builtin_amdgcn_global_load_lds( \
        (const AS1 unsigned int*)(gA + (size_t)(16 * (i)) * KD + (size_t)(t) * BK + soff), \
        (AS3 unsigned int*)(&lsA[b][16 * (i) * BK]), 16, 0, 0)
#define SB(i, t, b) do { \
        const int r0 = 16 * (i); \
        const int grow = (r0 >> 6) * NHID + n0c + (r0 & 63); \
        __builtin_amdgcn_global_load_lds( \
            (const AS1 unsigned int*)(Bm + (size_t)grow * KD + (size_t)(t) * BK + soff), \
            (AS3 unsigned int*)(&lsB[b][r0 * BK]), 16, 0, 0); \
    } while (0)
    // per-wave staging: A instrs {w, w+8}; B instrs {w, w+8} + {w+16 if w<4}
#define STAGE(t, b) do { \
        SA(w, t, b); SA(w + 8, t, b); \
        SB(w, t, b); SB(w + 8, t, b); \
        if (w < 4) SB(w + 16, t, b); \
    } while (0)

    // fragment read rows + hoisted swizzled slot offsets (ushort units)
    const int arow = wm * 64 + l31;    // + 32*m
    const int brow = wn * 32 + l31;    // + 64*p
    const int kkey = (l31 >> 1) & 3;
    const int cs0h = ((0 + hi) ^ kkey) << 3;   // s=0
    const int cs1h = ((2 + hi) ^ kkey) << 3;   // s=1

    f32x16 acc[2][5] = {};

    // prologue: stage tiles 0,1 into bufs 0,1
    STAGE(0, 0);
    STAGE(1, 1);
    asm volatile("s_waitcnt vmcnt(4)" ::: "memory");   // tile-0 loads done
    __builtin_amdgcn_s_barrier();

    int bc = 0, bn1 = 1, bn2 = 2;
    for (int kt = 0; kt < NT; ++kt) {
        if (kt < NT - 2) STAGE(kt + 2, bn2);
        #pragma unroll
        for (int s = 0; s < 2; ++s) {
            const int cs = s ? cs1h : cs0h;
            short8 av[2], bv[5];
            #pragma unroll
            for (int m = 0; m < 2; ++m)
                av[m] = *(const short8*)&lsA[bc][(arow + 32 * m) * BK + cs];
            #pragma unroll
            for (int p = 0; p < 5; ++p)
                bv[p] = *(const short8*)&lsB[bc][(brow + 64 * p) * BK + cs];
            __builtin_amdgcn_s_setprio(1);
            #pragma unroll
            for (int m = 0; m < 2; ++m)
                #pragma unroll
                for (int p = 0; p < 5; ++p)
                    MFMA32(acc[m][p], av[m], bv[p]);
            __builtin_amdgcn_s_setprio(0);
        }
        // counted wait: own this-tile issues (<=4-5) stay in flight; all older
        // (tile kt+1's data, issued at kt-1) retired in-order -> safe to flip.
        if (kt < NT - 2) asm volatile("s_waitcnt vmcnt(4)" ::: "memory");
        else             asm volatile("s_waitcnt vmcnt(0)" ::: "memory");
        __builtin_amdgcn_s_barrier();
        const int tmp = bc; bc = bn1; bn1 = bn2; bn2 = tmp;
    }

    // ---- fused epilogue ----
    // C/D layout (32x32): col = lane&31, row = (reg&3) + 8*(reg>>2) + 4*hi
    const int col = n0c + wn * 32 + l31;
    const float bgv  = bg[col];
    const float bhv  = bh[col];
    const float bfv  = bfg[col] + bfh[col];
    const float bpv  = bp[col];
    const size_t PL = (size_t)MDIM * NHID;
    #pragma unroll
    for (int m = 0; m < 2; ++m) {
        #pragma unroll
        for (int q = 0; q < 4; ++q) {
            #pragma unroll
            for (int t = 0; t < 4; ++t) {
                const int e = q * 4 + t;
                const int row = m0 + wm * 64 + m * 32 + q * 8 + 4 * hi + t;
                float gx = acc[m][0][e] + bgv;
                float hx = acc[m][1][e] + bhv;
                float sx = acc[m][2][e] + acc[m][3][e] + bfv;
                float tg = __expf(-2.0f * fabsf(gx));
                float g  = __builtin_copysignf((1.0f - tg) / (1.0f + tg), gx);
                float th = __expf(-2.0f * fabsf(hx));
                float hh = __builtin_copysignf((1.0f - th) / (1.0f + th), hx);
                float gate = 1.0f / (1.0f + __expf(-sx));
                float nh = g * (1.0f - gate) + gate * hh;
                float y  = acc[m][4][e] + bpv + nh;
                out[(size_t)row * NHID + col]      = y;
                out[PL + (size_t)row * NHID + col] = nh;
            }
        }
    }
#undef SA
#undef SB
#undef STAGE
}

extern "C" void kernel_launch(void* const* d_in, const int* in_sizes, int n_in,
                              void* d_out, int out_size, void* d_ws, size_t ws_size,
                              hipStream_t stream) {
    const float* x      = (const float*)d_in[0];
    const float* hidden = (const float*)d_in[1];
    const float* mask   = (const float*)d_in[2];
    const float* Wg     = (const float*)d_in[3];
    const float* bg     = (const float*)d_in[4];
    const float* Wh     = (const float*)d_in[5];
    const float* bh     = (const float*)d_in[6];
    const float* Wfg    = (const float*)d_in[7];
    const float* bfg    = (const float*)d_in[8];
    const float* Wfh    = (const float*)d_in[9];
    const float* bfh    = (const float*)d_in[10];
    const float* Wp     = (const float*)d_in[11];
    const float* bp     = (const float*)d_in[12];
    float* out = (float*)d_out;

    const size_t need = (size_t)MDIM * KD * 2 + (size_t)5 * NHID * KD * 2;
    if (ws_size < need) return;

    unsigned short* xc = (unsigned short*)d_ws;
    unsigned short* Wm = xc + (size_t)MDIM * KD;

    prep_xc<<<MDIM * KD / 8 / 256, 256, 0, stream>>>(x, hidden, xc);
    prep_wm<<<NHID * KD / 4 / 256, 256, 0, stream>>>(Wg, Wh, Wfg, Wfh, Wp, mask, Wm);
    dim3 grid(NHID / 64, MDIM / 256);
    gemm_fused<<<grid, 512, 0, stream>>>(xc, Wm, bg, bh, bfg, bfh, bp, out);
}